// Round 4
// baseline (298.541 us; speedup 1.0000x reference)
//
#include <hip/hip_runtime.h>
#include <math.h>

#define Bn 64
#define In 2048
#define On 2048
#define Sn 10
#define Cn 512

#define KT 64              // K tile
#define NT (In / KT)       // 32 K-tiles
#define LROW 72            // LDS row stride in bf16 elems (KT + 8)
#define NR 16              // LDS rows: 10 dendrite + 1 weight + 5 zero pad

typedef short short8 __attribute__((ext_vector_type(8)));
typedef float f32x4 __attribute__((ext_vector_type(4)));

__device__ __forceinline__ unsigned short f2bf(float f) {
    union { float f; unsigned u; } v; v.f = f;
    unsigned r = (v.u + 0x7FFFu + ((v.u >> 16) & 1u)) >> 16;  // RNE
    return (unsigned short)r;
}
__device__ __forceinline__ float sigmoidf_(float x) { return 1.0f / (1.0f + expf(-x)); }

// blocks 0..63: ctx_signal[b] = mean(context[b,:]); blocks 64..575: x -> bf16
__global__ void prep_kernel(const float* __restrict__ x,
                            const float* __restrict__ ctx,
                            float* __restrict__ ws_ctx,
                            unsigned short* __restrict__ ws_xbf) {
    const int b = blockIdx.x;
    const int t = threadIdx.x;
    if (b < Bn) {
        __shared__ float red[256];
        float s = ctx[b * Cn + t] + ctx[b * Cn + t + 256];
        red[t] = s;
        __syncthreads();
        for (int off = 128; off > 0; off >>= 1) {
            if (t < off) red[t] += red[t + off];
            __syncthreads();
        }
        if (t == 0) ws_ctx[b] = red[0] * (1.0f / (float)Cn);
    } else {
        int idx = (b - Bn) * 256 + t;
        ws_xbf[idx] = f2bf(x[idx]);
    }
}

// One wave (64 threads) per output channel o. NO barriers anywhere:
// the wave stages its own B-tile into wave-private LDS (in-order lgkmcnt),
// so all 2048 waves free-run and keep the memory system continuously fed.
__global__ __launch_bounds__(64, 2)
void main_kernel(const unsigned short* __restrict__ xbf,
                 const float* __restrict__ wgt,
                 const float* __restrict__ cst,
                 const float* __restrict__ seg,
                 const float* __restrict__ bias,
                 const float* __restrict__ aact,
                 const float* __restrict__ athr,
                 const float* __restrict__ gates,
                 const float* __restrict__ prn,
                 const float* __restrict__ ws_ctx,
                 float* __restrict__ out) {
    __shared__ __align__(16) unsigned short Blds[2][NR * LROW];

    const int lane = threadIdx.x;       // 0..63
    const int o = blockIdx.x;           // one o per wave
    const int l15 = lane & 15;
    const int q = lane >> 4;
    const float pthr = prn[0];

    // zero pad rows 11..15 of both buffers (in-wave order guarantees visibility)
    for (int idx = lane; idx < 5 * LROW; idx += 64) {
        Blds[0][11 * LROW + idx] = 0;
        Blds[1][11 * LROW + idx] = 0;
    }

    // mean_astro: lane-parallel over batch, xor-reduce (all lanes get result)
    const float aa = aact[o], th = athr[o];
    float sg = sigmoidf_(ws_ctx[lane] * aa);
    float ma = (sg > th) ? sg : 0.0f;
#pragma unroll
    for (int m = 32; m; m >>= 1) ma += __shfl_xor(ma, m, 64);
    const float mastro = ma * (1.0f / (float)Bn);

    // dendritic gate sigmoid for this lane's n-row
    const float gsig = (l15 < 10) ? sigmoidf_(gates[o * Sn + l15]) : 0.0f;

    // seg flat staging: 320 float2 per K-tile chunk (contiguous 2560 B),
    // lane handles f = lane + 64j, j=0..4 (fully coalesced 512 B per instr)
    int sego[5], ldso[5];
#pragma unroll
    for (int j = 0; j < 5; ++j) {
        const int f = lane + 64 * j;
        const int io = f / 5;              // i within tile, 0..63
        const int s2 = (f - io * 5) * 2;   // s in {0,2,4,6,8}; pair (s2,s2+1)
        sego[j] = io * Sn + s2;            // float offset within chunk
        ldso[j] = s2 * LROW + io;          // LDS elem offset
    }
    const float* segbase = seg + (size_t)o * In * Sn;  // +t*KT*Sn per tile
    const float* wrow = wgt + (size_t)o * In;
    const float* crow = cst + (size_t)o * In;
    const unsigned short* xrow = xbf + (size_t)l15 * In + q * 8;

    // staging register sets (tile-parity named; all indices compile-time)
    float2 SA[5], SB[5];
    float wA, cA, wB, cB;
    short8 AA[4][2], AB[4][2];

    f32x4 acc[4];
#pragma unroll
    for (int mt = 0; mt < 4; ++mt) acc[mt] = (f32x4){0.f, 0.f, 0.f, 0.f};

    auto loadSeg = [&](float2 (&S)[5], float& w, float& c, int t) {
        const float* p = segbase + t * (KT * Sn);
#pragma unroll
        for (int j = 0; j < 5; ++j) S[j] = *(const float2*)(p + sego[j]);
        w = wrow[t * KT + lane];
        c = crow[t * KT + lane];
    };
    auto loadA = [&](short8 (&A)[4][2], int t) {
#pragma unroll
        for (int mt = 0; mt < 4; ++mt) {
            const unsigned short* p = xrow + (size_t)mt * 16 * In + t * KT;
            A[mt][0] = *(const short8*)(p);
            A[mt][1] = *(const short8*)(p + 32);
        }
    };
    auto storeT = [&](float2 (&S)[5], float w, float c, int bb) {
        unsigned short* B = Blds[bb];
#pragma unroll
        for (int j = 0; j < 5; ++j) {
            B[ldso[j]] = f2bf(S[j].x);
            B[ldso[j] + LROW] = f2bf(S[j].y);
        }
        const float e = (__builtin_fabsf(w) * c > pthr) ? w : 0.0f;
        B[10 * LROW + lane] = f2bf(e);
    };
    auto computeT = [&](short8 (&A)[4][2], int bb) {
        const unsigned short* Bp = &Blds[bb][l15 * LROW + q * 8];
        short8 b0 = *(const short8*)(Bp);
        short8 b1 = *(const short8*)(Bp + 32);
#pragma unroll
        for (int mt = 0; mt < 4; ++mt) {
            acc[mt] = __builtin_amdgcn_mfma_f32_16x16x32_bf16(A[mt][0], b0, acc[mt], 0, 0, 0);
            acc[mt] = __builtin_amdgcn_mfma_f32_16x16x32_bf16(A[mt][1], b1, acc[mt], 0, 0, 0);
        }
    };

    // ---- barrier-free double-buffered K loop (unrolled x2, branch-free) ----
    loadSeg(SA, wA, cA, 0);
    loadSeg(SB, wB, cB, 1);
    loadA(AA, 0);
    storeT(SA, wA, cA, 0);           // tile 0 -> buf0
    for (int u = 0; u < NT / 2; ++u) {
        const int t = 2 * u;
        const int tp1 = (t + 1 < NT) ? t + 1 : NT - 1;
        const int tp2 = (t + 2 < NT) ? t + 2 : NT - 1;
        const int tp3 = (t + 3 < NT) ? t + 3 : NT - 1;
        // even: tile t in buf0
        loadSeg(SA, wA, cA, tp2);    // regs free (tile t written last odd half)
        loadA(AB, tp1);
        computeT(AA, 0);
        storeT(SB, wB, cB, 1);       // tile t+1 (loaded one iter ago; counted vmcnt)
        // odd: tile t+1 in buf1
        loadSeg(SB, wB, cB, tp3);
        loadA(AA, tp2);
        computeT(AB, 1);
        storeT(SA, wA, cA, 0);       // tile t+2 (junk on last iter: never read)
    }

    // ---- epilogue: cross-lane reduce over n (l15), no LDS, no atomics ----
    // acc[mt][r] = D[b = mt*16 + q*4 + r][n = l15]
    const float bo = bias[o];
#pragma unroll
    for (int mt = 0; mt < 4; ++mt) {
#pragma unroll
        for (int r = 0; r < 4; ++r) {
            const float v = acc[mt][r];
            float contrib;
            if (l15 < 10)       contrib = (v > 0.f ? v : 0.f) * gsig;  // dendrite
            else if (l15 == 10) contrib = mastro * v;                  // synaptic
            else                contrib = 0.f;                          // pad
            contrib += __shfl_xor(contrib, 1, 64);
            contrib += __shfl_xor(contrib, 2, 64);
            contrib += __shfl_xor(contrib, 4, 64);
            contrib += __shfl_xor(contrib, 8, 64);
            if (l15 == 0) {
                const int b = mt * 16 + q * 4 + r;
                const float ov = contrib + bo;
                out[(size_t)b * On + o] = ov > 0.f ? ov : 0.f;
            }
        }
    }
}

extern "C" void kernel_launch(void* const* d_in, const int* in_sizes, int n_in,
                              void* d_out, int out_size, void* d_ws, size_t ws_size,
                              hipStream_t stream) {
    (void)in_sizes; (void)n_in; (void)out_size; (void)ws_size;
    const float* x    = (const float*)d_in[0];
    const float* ctx  = (const float*)d_in[1];
    // d_in[2] prev_activation: unused by the reference
    const float* wgt  = (const float*)d_in[3];
    const float* bias = (const float*)d_in[4];
    const float* aact = (const float*)d_in[5];
    const float* athr = (const float*)d_in[6];
    const float* seg  = (const float*)d_in[7];
    const float* gat  = (const float*)d_in[8];
    const float* cst  = (const float*)d_in[9];
    const float* prn  = (const float*)d_in[10];
    float* out = (float*)d_out;

    float* ws_ctx = (float*)d_ws;
    unsigned short* ws_xbf = (unsigned short*)((char*)d_ws + 256);

    prep_kernel<<<Bn + (Bn * In) / 256, 256, 0, stream>>>(x, ctx, ws_ctx, ws_xbf);
    main_kernel<<<On, 64, 0, stream>>>(ws_xbf, wgt, cst, seg, bias, aact,
                                       athr, gat, prn, ws_ctx, out);
}